// Round 7
// baseline (371.109 us; speedup 1.0000x reference)
//
#include <hip/hip_runtime.h>
#include <stdint.h>

// Problem constants
#define SEQ   2048
#define NNODE 16384      // B*S = 8*2048

typedef short  short8  __attribute__((ext_vector_type(8)));   // 8 bf16 (4 VGPR)
typedef float  float4v __attribute__((ext_vector_type(4)));
typedef unsigned short u16;
typedef unsigned short u16x8 __attribute__((ext_vector_type(8)));
typedef short  short4v __attribute__((ext_vector_type(4)));

__device__ __forceinline__ float b2f(u16 u) {
    union { unsigned int i; float f; } x; x.i = ((unsigned int)u) << 16; return x.f;
}
__device__ __forceinline__ u16 f2b(float f) {
    union { float f; unsigned int i; } x; x.f = f;
    unsigned int u = x.i;
    unsigned int r = (u + 0x7fffu + ((u >> 16) & 1u)) >> 16;  // RNE
    return (u16)r;
}

__device__ __forceinline__ void gld16(const void* g, void* l) {
    __builtin_amdgcn_global_load_lds(
        (const __attribute__((address_space(1))) void*)g,
        (__attribute__((address_space(3))) void*)l, 16, 0, 0);
}

struct GemmP {
    const void*  A[2];
    const u16*   B[2];
    const float* bias[2];
    u16*         out[2];
};

// ---------------------------------------------------------------------------
// Fine-phase 256x128-tile bf16 GEMM (T3+T4+T5, r5-verified skeleton) with
// FUSED fp32->bf16 A-staging (AF32=1, r1-proven reg pattern):
//   512 thr = 8 waves (4M x 2N), per-wave 64x64 out, acc[4][4].
//   BK=64, LDS ring-3 (3 x (A 32KB + B 16KB) = 144 KB, 1 blk/CU).
//   Per K-tile, 2 phases, each: { 8 ds_read_b128 | stage | [vmcnt(N)] |
//     s_barrier | lgkmcnt(0) | setprio(1) 16 MFMA setprio(0) | s_barrier }.
//   bf16 path: ph0 stages A(T+2) via gld16 (4), ph1 stages B(T+2) (2),
//     vmcnt(6) at ph1 (= tile T+2's 6 loads outstanding -> T+1 landed).
//   AF32 path: ph0 issues 8 float4 loads A(T+2)->pa ping-pong; ph1 stages
//     B(T+2) via gld16 (2) + cvt/ds_writes pa(T+1) -> A-slot(T+1);
//     vmcnt(10) (= pa(T+2)8 + B(T+2)2 younger than B(T+1)); the MFMA's
//     lgkmcnt(0) + end barrier publish the ds_writes before T+1 reads.
//     pa cover = 3 phases (issued T-1 ph0 style, consumed T ph1) >> HBM lat.
//   vmcnt NEVER drains to 0 in the loop.
//   Swizzle: 16B-chunk index ^= (row & 7) on BOTH gld16/vector-load global
//   source and ds_read address (involution; LDS dest linear).
//   XCD-chunked block swizzle (T1): flat 256 blocks -> xcd=flat&7 owns a
//   contiguous mt range so the 4 nt-blocks sharing an A-panel hit one L2.
//   Epilogue: acc -> LDS (stride 136 u16) -> dwordx4 stores after full
//   __syncthreads() drain.
// ---------------------------------------------------------------------------
#define NOVM
#define VM6  asm volatile("s_waitcnt vmcnt(6)" ::: "memory");
#define VM10 asm volatile("s_waitcnt vmcnt(10)" ::: "memory");

#define PHASE(ASL, BSL, KH, STAGE, VMW)                                       \
    {                                                                         \
        short8 af[4], bq[4];                                                  \
        _Pragma("unroll") for (int mi = 0; mi < 4; ++mi)                      \
            af[mi] = *(const short8*)((ASL) +                                 \
                (size_t)(wm * 64 + mi * 16 + lr) * 64 +                       \
                (((KH) * 4 + lk) ^ (lr & 7)) * 8);                            \
        _Pragma("unroll") for (int ni = 0; ni < 4; ++ni)                      \
            bq[ni] = *(const short8*)((BSL) +                                 \
                (size_t)(wn * 64 + ni * 16 + lr) * 64 +                       \
                (((KH) * 4 + lk) ^ (lr & 7)) * 8);                            \
        STAGE;                                                                \
        VMW                                                                   \
        __builtin_amdgcn_s_barrier();                                         \
        asm volatile("s_waitcnt lgkmcnt(0)" ::: "memory");                    \
        __builtin_amdgcn_s_setprio(1);                                        \
        _Pragma("unroll") for (int mi = 0; mi < 4; ++mi)                      \
            _Pragma("unroll") for (int ni = 0; ni < 4; ++ni)                  \
                acc[mi][ni] = __builtin_amdgcn_mfma_f32_16x16x32_bf16(        \
                    af[mi], bq[ni], acc[mi][ni], 0, 0, 0);                    \
        __builtin_amdgcn_s_setprio(0);                                        \
        __builtin_amdgcn_s_barrier();                                         \
    }

template <int ACT, int AF32>
__global__ __launch_bounds__(512, 2) void gemmt_k(GemmP p, int M, int N, int K) {
    __shared__ __align__(16) u16 smem[73728];   // 144 KB

    const int z = blockIdx.z;
    const u16*   __restrict__ A16  = (const u16*)p.A[z];
    const float* __restrict__ A32  = (const float*)p.A[z];
    const u16*   __restrict__ Bg   = p.B[z];
    const float* __restrict__ bias = p.bias[z];

    // XCD-chunked bijective swizzle: 256 blocks, 8 XCDs, 32 tiles/XCD.
    const int flat = blockIdx.x;                       // 0..255
    const int swz  = ((flat & 7) << 5) | (flat >> 3);
    const int mt   = (swz >> 2) * 256;
    const int nt   = (swz & 3) * 128;

    const int tid = threadIdx.x;
    const int l   = tid & 63;
    const int w   = tid >> 6;
    const int wm  = w >> 1;           // 0..3  (64-row group)
    const int wn  = w & 1;            // 0..1  (64-col group)
    const int lr  = l & 15;
    const int lk  = l >> 4;
    (void)M;

    float4v acc[4][4] = {};
    float4v paA[8], paB[8];           // AF32 ping-pong A prefetch (fp32)

    // staging: thread t -> rows (t>>3)+64i, chunk-slot t&7;
    // global chunk = slot ^ (row&7)  (row&7 == srow&7 since 64i == 0 mod 8)
    const int srow   = tid >> 3;
    const int gchunk = (tid & 7) ^ (srow & 7);

    u16* const As0 = smem;            // A ring: 0, 16384, 32768 (u16)
    u16* const Bs0 = smem + 49152;    // B ring: +0, +8192, +16384

    auto stageA = [&](int k0, u16* dst) {
#pragma unroll
        for (int i = 0; i < 4; ++i)
            gld16(A16 + (size_t)(mt + srow + 64 * i) * K + k0 + gchunk * 8,
                  dst + (size_t)(tid + 512 * i) * 8);
    };
    auto stageB = [&](int k0, u16* dst) {
#pragma unroll
        for (int i = 0; i < 2; ++i)
            gld16(Bg + (size_t)(nt + srow + 64 * i) * K + k0 + gchunk * 8,
                  dst + (size_t)(tid + 512 * i) * 8);
    };
    auto prefA32 = [&](int k0, float4v* pa) {
#pragma unroll
        for (int i = 0; i < 4; ++i) {
            const float* s = A32 + (size_t)(mt + srow + 64 * i) * K
                                 + k0 + gchunk * 8;
            pa[2 * i]     = *(const float4v*)s;
            pa[2 * i + 1] = *(const float4v*)(s + 4);
        }
    };
    auto cvtWrite = [&](const float4v* pa, u16* dst) {
#pragma unroll
        for (int i = 0; i < 4; ++i) {
            const float4v a = pa[2 * i], b = pa[2 * i + 1];
            u16x8 r;
            r[0] = f2b(a[0]); r[1] = f2b(a[1]); r[2] = f2b(a[2]); r[3] = f2b(a[3]);
            r[4] = f2b(b[0]); r[5] = f2b(b[1]); r[6] = f2b(b[2]); r[7] = f2b(b[3]);
            *(u16x8*)(dst + (size_t)(tid + 512 * i) * 8) = r;
        }
    };

    const int NT = K >> 6;   // K-tiles of 64 (16 for GEMM1, 8 for GEMM23)

    // ---- prologue: tiles 0,1; AF32 leaves A(1) in paB ----
    if constexpr (AF32) {
        float4v p0[8];
        prefA32(0, p0);                  // 8
        stageB(0, Bs0);                  // 2
        prefA32(64, paB);                // 8   A(1)
        stageB(64, Bs0 + 8192);          // 2
        cvtWrite(p0, As0);               // compiler drains p0 (oldest 8)
        asm volatile("s_waitcnt vmcnt(10)" ::: "memory");   // B(0) landed
        asm volatile("s_waitcnt lgkmcnt(0)" ::: "memory");  // A(0) writes in
    } else {
        stageA(0, As0);          stageB(0, Bs0);
        stageA(64, As0 + 16384); stageB(64, Bs0 + 8192);
        asm volatile("s_waitcnt vmcnt(6)" ::: "memory");    // tile 0 landed
    }
    __builtin_amdgcn_s_barrier();

    // ---- main loop: 2 tiles/iter, ring slot sc = T%3 ----
    int sc = 0;
    for (int T = 0; T < NT; T += 2) {
        const int sc1 = (sc == 2) ? 0 : sc + 1;
        const int sc2 = (sc1 == 2) ? 0 : sc1 + 1;
        u16* Ac = As0 + sc  * 16384;  u16* Bc = Bs0 + sc  * 8192;
        u16* Ao = As0 + sc1 * 16384;  u16* Bo = Bs0 + sc1 * 8192;
        u16* A2 = As0 + sc2 * 16384;  u16* B2 = Bs0 + sc2 * 8192;
        const int k2 = (T + 2 < NT) ? (T + 2) << 6 : 0;   // clamp keeps vmcnt
        const int k3 = (T + 3 < NT) ? (T + 3) << 6 : 0;   // counts uniform
        if constexpr (AF32) {
            // even tile T: pa_cur=paA<-A(T+2); ph1 writes paB=A(T+1)->slot sc1
            PHASE(Ac, Bc, 0, prefA32(k2, paA), NOVM)
            PHASE(Ac, Bc, 1, { stageB(k2, B2); cvtWrite(paB, Ao); }, VM10)
            // odd tile T+1: pa_cur=paB<-A(T+3); ph1 writes paA=A(T+2)->slot sc2
            PHASE(Ao, Bo, 0, prefA32(k3, paB), NOVM)
            PHASE(Ao, Bo, 1, { stageB(k3, Bc); cvtWrite(paA, A2); }, VM10)
        } else {
            PHASE(Ac, Bc, 0, stageA(k2, A2), NOVM)
            PHASE(Ac, Bc, 1, stageB(k2, B2), VM6)
            PHASE(Ao, Bo, 0, stageA(k3, Ac), NOVM)
            PHASE(Ao, Bo, 1, stageB(k3, Bc), VM6)
        }
        sc = sc2;
    }

    __syncthreads();   // full drain: tail DMA/writes must land before LDS reuse

    // ---- epilogue: C/D layout col=lane&15, row=(lane>>4)*4+reg ----
    const int er0 = lk * 4;
    float bvv[4];
#pragma unroll
    for (int ni = 0; ni < 4; ++ni) bvv[ni] = bias[nt + wn * 64 + ni * 16 + lr];
#pragma unroll
    for (int mi = 0; mi < 4; ++mi)
#pragma unroll
        for (int ni = 0; ni < 4; ++ni) {
            const int lc = wn * 64 + ni * 16 + lr;
#pragma unroll
            for (int r = 0; r < 4; ++r) {
                float v = acc[mi][ni][r] + bvv[ni];
                if (ACT) v = v > 0.f ? v : 0.01f * v;
                smem[(size_t)(wm * 64 + mi * 16 + er0 + r) * 136 + lc] = f2b(v);
            }
        }
    __syncthreads();
#pragma unroll
    for (int it = 0; it < 8; ++it) {
        const int id  = it * 512 + tid;
        const int row = id >> 4, colc = id & 15;
        u16x8 vv = *(const u16x8*)(smem + (size_t)row * 136 + colc * 8);
        *(u16x8*)(p.out[z] + (size_t)(mt + row) * N + nt + colc * 8) = vv;
    }
}

// ---------------------------------------------------------------------------
// LDS-tiled weight transpose+convert: fp32 [K,N] -> bf16 [N,K], 64x64 tiles
// ---------------------------------------------------------------------------
struct TP { const float* src[6]; u16* dst[6]; int K[6]; int N[6]; };

__global__ __launch_bounds__(256) void transpose_k(TP t) {
    __shared__ float tile[64][65];
    const int m = blockIdx.y;
    const int K = t.K[m], N = t.N[m];
    const int tn = N >> 6;
    const int ntiles = (K >> 6) * tn;
    const int bid = blockIdx.x;
    if (bid >= ntiles) return;
    const int k0 = (bid / tn) * 64, n0 = (bid % tn) * 64;
    const int tid = threadIdx.x;
#pragma unroll
    for (int pass = 0; pass < 4; ++pass) {
        int kk = pass * 16 + (tid >> 4);
        int nn = (tid & 15) * 4;
        float4v v = *(const float4v*)(t.src[m] + (size_t)(k0 + kk) * N + n0 + nn);
        tile[kk][nn + 0] = v[0]; tile[kk][nn + 1] = v[1];
        tile[kk][nn + 2] = v[2]; tile[kk][nn + 3] = v[3];
    }
    __syncthreads();
    const int n = tid >> 2, kc = (tid & 3) * 16;
    u16x8 a, b;
#pragma unroll
    for (int j = 0; j < 8; ++j) {
        a[j] = f2b(tile[kc + j][n]);
        b[j] = f2b(tile[kc + 8 + j][n]);
    }
    u16* d = t.dst[m] + (size_t)(n0 + n) * K + k0 + kc;
    *(u16x8*)d = a;
    *(u16x8*)(d + 8) = b;
}

// EW[t][c] = sum_e emb[t][e] * W_edge[e][c]  (64x256 fp32, 4 partials for ILP)
__global__ void ew_k(const float* emb, const float* W_edge, float* EW) {
    const int t = blockIdx.x, c = threadIdx.x;
    float p0 = 0.f, p1 = 0.f, p2 = 0.f, p3 = 0.f;
    for (int e = 0; e < 64; e += 4) {
        p0 += emb[t * 64 + e + 0] * W_edge[(e + 0) * 256 + c];
        p1 += emb[t * 64 + e + 1] * W_edge[(e + 1) * 256 + c];
        p2 += emb[t * 64 + e + 2] * W_edge[(e + 2) * 256 + c];
        p3 += emb[t * 64 + e + 3] * W_edge[(e + 3) * 256 + c];
    }
    EW[t * 256 + c] = (p0 + p1) + (p2 + p3);
}

// ---------------------------------------------------------------------------
// GEMM2+GEMM3 fold: xcat = x1@(W2@Wcat) + (b2@Wcat + bcat)
// ---------------------------------------------------------------------------
struct WmP { const float* W2[2]; const float* Wmsg; const float* Wself;
             float* W23[2]; };

__global__ __launch_bounds__(512) void wmul_k(WmP q) {
    __shared__ float w2[16][256];
    const int side = blockIdx.y;
    const int k0 = blockIdx.x * 16;
    const int n = threadIdx.x;
    const float* __restrict__ W2 = q.W2[side];
    for (int i = threadIdx.x; i < 4096; i += 512)
        w2[i >> 8][i & 255] = W2[(size_t)(k0 + (i >> 8)) * 256 + (i & 255)];
    __syncthreads();
    const float* __restrict__ Wc = (n < 256) ? q.Wmsg : q.Wself;
    const int nn = n & 255;
    float acc[16] = {};
    for (int c = 0; c < 256; c += 4) {
        const float wc0 = Wc[(c + 0) * 256 + nn];
        const float wc1 = Wc[(c + 1) * 256 + nn];
        const float wc2 = Wc[(c + 2) * 256 + nn];
        const float wc3 = Wc[(c + 3) * 256 + nn];
#pragma unroll
        for (int kk = 0; kk < 16; ++kk)
            acc[kk] += w2[kk][c] * wc0 + w2[kk][c + 1] * wc1 +
                       w2[kk][c + 2] * wc2 + w2[kk][c + 3] * wc3;
    }
    for (int kk = 0; kk < 16; ++kk)
        q.W23[side][(size_t)(k0 + kk) * 512 + n] = acc[kk];
}

// b23[side][n] = ([bmsg|bself])[n] + sum_c b2[side][c]*Wcat[c][n]
struct B23WP { const float* b2[2]; const float* bmsg; const float* bself;
               const float* Wmsg; const float* Wself; float* b23; };

__global__ void b23w_k(B23WP q) {
    const int side = blockIdx.x;
    const int n = threadIdx.x;   // 512 threads
    const float* __restrict__ W = (n < 256) ? q.Wmsg : q.Wself;
    const int nn = n & 255;
    const float* __restrict__ b2 = q.b2[side];
    float p[8] = {};
    for (int c = 0; c < 256; c += 8) {
#pragma unroll
        for (int j = 0; j < 8; ++j)
            p[j] += b2[c + j] * W[(c + j) * 256 + nn];
    }
    float s = (n < 256) ? q.bmsg[nn] : q.bself[nn];
    s += ((p[0] + p[1]) + (p[2] + p[3])) + ((p[4] + p[5]) + (p[6] + p[7]));
    q.b23[side * 512 + n] = s;
}

// ---------------------------------------------------------------------------
// Epilogue: out_i = xself[i] + valid_i*(xmsg[head_i] + EW[type_i]);
//           L2-normalize; accumulate per-batch sum (later /2048).
// alpha == valid exactly (dst=arange -> singleton segments -> softmax = 1).
// ---------------------------------------------------------------------------
struct EpiP {
    const u16* xcat[2];
    const int* den[2]; const int* spa[2]; const int* arc[2];
    const int* wty[2]; const int* wma[2];
    const float* EW; float* racc;
};

__global__ __launch_bounds__(256) void epi_k(EpiP p) {
    __shared__ float part[4][256];
    const int bx    = blockIdx.x;
    const int side  = bx >> 9;           // 512 blocks per side
    const int local = bx & 511;
    const int base  = local * 32;        // 32 nodes/block (same batch: 32|2048)
    const int b     = base >> 11;
    const int tid   = threadIdx.x;
    const int w = tid >> 6, l = tid & 63;

    const u16* __restrict__ xcat = p.xcat[side];

    float4v acc = {};
    for (int j = 0; j < 8; ++j) {
        const int i     = base + w * 8 + j;
        const int valid = p.den[side][i] * p.spa[side][i];
        const int srcn  = p.arc[side][i] + (i >> 11) * SEQ;
        const int t     = p.wty[side][i] * p.wma[side][i];
        short4v xs = *(const short4v*)(xcat + (size_t)i * 512 + 256 + l * 4);
        short4v xm = *(const short4v*)(xcat + (size_t)srcn * 512 + l * 4);
        float4v ew = *(const float4v*)(p.EW + (size_t)t * 256 + l * 4);
        const float vm = valid ? 1.f : 0.f;
        float4v v;
        v[0] = b2f((u16)xs[0]) + vm * (b2f((u16)xm[0]) + ew[0]);
        v[1] = b2f((u16)xs[1]) + vm * (b2f((u16)xm[1]) + ew[1]);
        v[2] = b2f((u16)xs[2]) + vm * (b2f((u16)xm[2]) + ew[2]);
        v[3] = b2f((u16)xs[3]) + vm * (b2f((u16)xm[3]) + ew[3]);
        float ss = v[0]*v[0] + v[1]*v[1] + v[2]*v[2] + v[3]*v[3];
        for (int m = 32; m >= 1; m >>= 1) ss += __shfl_xor(ss, m, 64);
        const float rn = 1.f / fmaxf(sqrtf(ss), 1e-12f);
        acc[0] += v[0] * rn; acc[1] += v[1] * rn;
        acc[2] += v[2] * rn; acc[3] += v[3] * rn;
    }
    part[w][l * 4 + 0] = acc[0];
    part[w][l * 4 + 1] = acc[1];
    part[w][l * 4 + 2] = acc[2];
    part[w][l * 4 + 3] = acc[3];
    __syncthreads();
    const float s = part[0][tid] + part[1][tid] + part[2][tid] + part[3][tid];
    atomicAdd(p.racc + ((size_t)side * 8 + b) * 256 + tid, s);
}

// out[side,b,c] = (racc[side,b,:]/2048) @ Wf[:,c] + bf[c]   (fp32 out)
__global__ void fin_k(const float* racc, const float* Wf, const float* bfv,
                      float* out) {
    __shared__ float r[256];
    const int bid = blockIdx.x;   // side*8 + b, 0..15
    const int tid = threadIdx.x;
    r[tid] = racc[bid * 256 + tid] * (1.f / 2048.f);
    __syncthreads();
    float s = bfv[tid];
    for (int k = 0; k < 256; ++k)
        s += r[k] * Wf[k * 256 + tid];
    out[bid * 256 + tid] = s;
}

// ---------------------------------------------------------------------------
extern "C" void kernel_launch(void* const* d_in, const int* in_sizes, int n_in,
                              void* d_out, int out_size, void* d_ws, size_t ws_size,
                              hipStream_t stream) {
    // setup_inputs() dict order; float tensors fp32, index tensors int32
    const float* h[2]   = {(const float*)d_in[0],  (const float*)d_in[1]};
    const int* den[2]   = {(const int*)d_in[4],  (const int*)d_in[11]};
    const int* spa[2]   = {(const int*)d_in[5],  (const int*)d_in[12]};
    const int* arc[2]   = {(const int*)d_in[7],  (const int*)d_in[14]};
    const int* wty[2]   = {(const int*)d_in[9],  (const int*)d_in[16]};
    const int* wma[2]   = {(const int*)d_in[10], (const int*)d_in[17]};
    const float* W1[2]  = {(const float*)d_in[18], (const float*)d_in[22]};
    const float* b1[2]  = {(const float*)d_in[19], (const float*)d_in[23]};
    const float* W2[2]  = {(const float*)d_in[20], (const float*)d_in[24]};
    const float* b2[2]  = {(const float*)d_in[21], (const float*)d_in[25]};
    const float* emb    = (const float*)d_in[26];
    const float* Wmsg   = (const float*)d_in[27];
    const float* bmsg   = (const float*)d_in[28];
    const float* Wedge  = (const float*)d_in[29];
    const float* Wself  = (const float*)d_in[31];
    const float* bself  = (const float*)d_in[32];
    const float* Wf     = (const float*)d_in[33];
    const float* bf_    = (const float*)d_in[34];

    char* ws = (char*)d_ws;
    size_t off = 0;
    auto alloc = [&](size_t bytes) -> void* {
        void* pp = ws + off; off += (bytes + 255) & ~(size_t)255; return pp;
    };
    u16*   x1    = (u16*)  alloc(2ull * NNODE * 512 * 2);   // 32 MB, MLP hidden
    u16*   xcat  = (u16*)  alloc(2ull * NNODE * 512 * 2);   // 32 MB, [msg|self]
    u16*   W1T   = (u16*)  alloc(2ull * 512 * 1024 * 2);
    float* W23   = (float*)alloc(2ull * 512 * 512 * 4);     // folded W2@Wcat
    u16*   W23T  = (u16*)  alloc(2ull * 512 * 512 * 2);
    float* EW    = (float*)alloc(64 * 256 * 4);
    float* b23   = (float*)alloc(2 * 512 * 4);
    float* racc  = (float*)alloc(2 * 8 * 256 * 4);

    // prep: W1 transpose+convert to [N,K] bf16
    TP tp = {};
    tp.src[0] = W1[0]; tp.dst[0] = W1T;              tp.K[0] = 1024; tp.N[0] = 512;
    tp.src[1] = W1[1]; tp.dst[1] = W1T + 512 * 1024; tp.K[1] = 1024; tp.N[1] = 512;
    hipLaunchKernelGGL(transpose_k, dim3(128, 2), dim3(256), 0, stream, tp);
    hipLaunchKernelGGL(ew_k, dim3(64), dim3(256), 0, stream, emb, Wedge, EW);

    // prep: fold W23 = W2@[Wmsg|Wself] (fp32), transpose to bf16 [N,K]
    WmP wq;
    wq.W2[0] = W2[0]; wq.W2[1] = W2[1];
    wq.Wmsg = Wmsg; wq.Wself = Wself;
    wq.W23[0] = W23; wq.W23[1] = W23 + 512 * 512;
    hipLaunchKernelGGL(wmul_k, dim3(32, 2), dim3(512), 0, stream, wq);

    TP tp2 = {};
    tp2.src[0] = W23;            tp2.dst[0] = W23T;            tp2.K[0] = 512; tp2.N[0] = 512;
    tp2.src[1] = W23 + 512*512;  tp2.dst[1] = W23T + 512*512;  tp2.K[1] = 512; tp2.N[1] = 512;
    hipLaunchKernelGGL(transpose_k, dim3(64, 2), dim3(256), 0, stream, tp2);

    B23WP bq;
    bq.b2[0] = b2[0]; bq.b2[1] = b2[1];
    bq.bmsg = bmsg; bq.bself = bself;
    bq.Wmsg = Wmsg; bq.Wself = Wself;
    bq.b23 = b23;
    hipLaunchKernelGGL(b23w_k, dim3(2), dim3(512), 0, stream, bq);
    hipMemsetAsync(racc, 0, 2 * 8 * 256 * 4, stream);

    // GEMM1 (fused fp32->bf16 A): [16384,1024]@[1024,512] + b1, leaky ReLU
    GemmP g1 = {};
    g1.A[0] = h[0]; g1.A[1] = h[1];
    g1.B[0] = W1T;  g1.B[1] = W1T + 512 * 1024;
    g1.bias[0] = b1[0]; g1.bias[1] = b1[1];
    g1.out[0] = x1; g1.out[1] = x1 + (size_t)NNODE * 512;
    hipLaunchKernelGGL((gemmt_k<1, 1>), dim3(256, 1, 2), dim3(512), 0, stream,
                       g1, NNODE, 512, 1024);

    // GEMM23 (folded): [16384,512]@[512,512] + b23 -> xcat
    GemmP g23 = {};
    g23.A[0] = x1;   g23.A[1] = x1 + (size_t)NNODE * 512;
    g23.B[0] = W23T; g23.B[1] = W23T + 512 * 512;
    g23.bias[0] = b23; g23.bias[1] = b23 + 512;
    g23.out[0] = xcat; g23.out[1] = xcat + (size_t)NNODE * 512;
    hipLaunchKernelGGL((gemmt_k<0, 0>), dim3(256, 1, 2), dim3(512), 0, stream,
                       g23, NNODE, 512, 512);

    // gather + mask + L2-normalize + per-batch mean accumulation
    EpiP ep;
    ep.xcat[0] = xcat; ep.xcat[1] = xcat + (size_t)NNODE * 512;
    for (int s = 0; s < 2; ++s) {
        ep.den[s] = den[s]; ep.spa[s] = spa[s]; ep.arc[s] = arc[s];
        ep.wty[s] = wty[s]; ep.wma[s] = wma[s];
    }
    ep.EW = EW; ep.racc = racc;
    hipLaunchKernelGGL(epi_k, dim3(1024), dim3(256), 0, stream, ep);

    // final projection -> d_out (fp32, src then tgt, 2*8*256)
    hipLaunchKernelGGL(fin_k, dim3(16), dim3(256), 0, stream,
                       racc, Wf, bf_, (float*)d_out);
}

// Round 8
// 302.532 us; speedup vs baseline: 1.2267x; 1.2267x over previous
//
#include <hip/hip_runtime.h>
#include <stdint.h>

// Problem constants
#define SEQ   2048
#define NNODE 16384      // B*S = 8*2048

typedef short  short8  __attribute__((ext_vector_type(8)));   // 8 bf16 (4 VGPR)
typedef float  float4v __attribute__((ext_vector_type(4)));
typedef unsigned short u16;
typedef unsigned short u16x8 __attribute__((ext_vector_type(8)));
typedef short  short4v __attribute__((ext_vector_type(4)));

__device__ __forceinline__ float b2f(u16 u) {
    union { unsigned int i; float f; } x; x.i = ((unsigned int)u) << 16; return x.f;
}
__device__ __forceinline__ u16 f2b(float f) {
    union { float f; unsigned int i; } x; x.f = f;
    unsigned int u = x.i;
    unsigned int r = (u + 0x7fffu + ((u >> 16) & 1u)) >> 16;  // RNE
    return (u16)r;
}

__device__ __forceinline__ void gld16(const void* g, void* l) {
    __builtin_amdgcn_global_load_lds(
        (const __attribute__((address_space(1))) void*)g,
        (__attribute__((address_space(3))) void*)l, 16, 0, 0);
}

struct GemmP {
    const void*  A[2];
    const u16*   B[2];
    const float* bias[2];
    u16*         out[2];
};

template <int MB>
__device__ __forceinline__ void mfma4(const short8* af, const short8* bq,
                                      float4v (*acc)[4]) {
#pragma unroll
    for (int mi = 0; mi < 4; ++mi)
#pragma unroll
        for (int ni = 0; ni < 4; ++ni)
            acc[MB + mi][ni] = __builtin_amdgcn_mfma_f32_16x16x32_bf16(
                af[mi], bq[ni], acc[MB + mi][ni], 0, 0, 0);
}

// ---------------------------------------------------------------------------
// COARSE 128x128-tile GEMM with fused fp32->bf16 A staging (r1/r3 verbatim,
// measured 69.8-70.9us on GEMM1). Used ONLY for GEMM1: at 2 blk/CU the
// conversion VALU + LDS writes hide under cross-block TLP — the fine-phase
// lockstep schedule cannot hide them (r7: 107us) and a separate cvt pass
// costs 35-55us of extra HBM round-trip (r5). Coarse-fused wins net.
// ---------------------------------------------------------------------------
#define TILE_BODY(AC, BC, KN, AG, BG, ACV, PL, PC)                            \
    {                                                                         \
        short8 bq[4], af[4];                                                  \
        _Pragma("unroll") for (int ni = 0; ni < 4; ++ni)                      \
            bq[ni] = *(const short8*)((BC) + boff + ni * 512);                \
        _Pragma("unroll") for (int mi = 0; mi < 4; ++mi)                      \
            af[mi] = *(const short8*)((AC) + aoff + mi * 512);                \
        if constexpr (AF32) prefA32(KN, PL); else stageA16(KN, AG);           \
        __builtin_amdgcn_s_barrier();                                         \
        __builtin_amdgcn_s_setprio(1);                                        \
        mfma4<0>(af, bq, acc);                                                \
        __builtin_amdgcn_s_setprio(0);                                        \
        __builtin_amdgcn_s_barrier();                                         \
        _Pragma("unroll") for (int mi = 0; mi < 4; ++mi)                      \
            af[mi] = *(const short8*)((AC) + aoff + (4 + mi) * 512);          \
        stageB(KN, BG);                                                       \
        if constexpr (AF32) {                                                 \
            cvtWrite(PC, ACV);                                                \
            asm volatile("s_waitcnt lgkmcnt(0)" ::: "memory");                \
            asm volatile("s_waitcnt vmcnt(8)" ::: "memory");                  \
        } else {                                                              \
            asm volatile("s_waitcnt vmcnt(8)" ::: "memory");                  \
        }                                                                     \
        __builtin_amdgcn_s_barrier();                                         \
        __builtin_amdgcn_s_setprio(1);                                        \
        mfma4<4>(af, bq, acc);                                                \
        __builtin_amdgcn_s_setprio(0);                                        \
        __builtin_amdgcn_s_barrier();                                         \
    }

template <int ACT, int AF32>
__global__ __launch_bounds__(512, 2) void gemm8_k(GemmP p, int M, int N, int K) {
    __shared__ __align__(16) u16 smem[49152];   // 96 KB

    const int z = blockIdx.z;
    const u16*   __restrict__ Bg   = p.B[z];
    const float* __restrict__ bias = p.bias[z];
    const u16*   __restrict__ A16  = (const u16*)p.A[z];
    const float* __restrict__ A32  = (const float*)p.A[z];

    const int mt  = blockIdx.x * 256;
    const int nt  = blockIdx.y * 256;
    const int tid = threadIdx.x;
    const int l   = tid & 63;
    const int w   = tid >> 6;
    const int wm  = (w >> 2) * 128;
    const int wn  = (w & 3) * 64;
    const int lr  = l & 15;
    const int lk  = l >> 4;
    (void)M;

    float4v acc[8][4] = {};
    float4v paA[4], paB[4];

    const int rm0 = tid >> 2;
    const int cc0 = tid & 3;
    const int gc0 = cc0 ^ (rm0 & 3) ^ ((rm0 >> 2) & 3);
    const int rm1 = rm0 + 128;

    u16* const As0 = smem;           // A ring: 0,8192,16384 (u16)
    u16* const Bs0 = smem + 24576;   // B ring: +0,+8192,+16384

    auto stageA16 = [&](int k0, u16* dst) {
        gld16(A16 + (size_t)(mt + rm0) * K + k0 + gc0 * 8, dst + tid * 8);
        gld16(A16 + (size_t)(mt + rm1) * K + k0 + gc0 * 8, dst + (tid + 512) * 8);
    };
    auto stageB = [&](int k0, u16* dst) {
        gld16(Bg + (size_t)(nt + rm0) * K + k0 + gc0 * 8, dst + tid * 8);
        gld16(Bg + (size_t)(nt + rm1) * K + k0 + gc0 * 8, dst + (tid + 512) * 8);
    };
    auto prefA32 = [&](int k0, float4v* pa) {
        const float* s0 = A32 + (size_t)(mt + rm0) * K + k0 + gc0 * 8;
        const float* s1 = A32 + (size_t)(mt + rm1) * K + k0 + gc0 * 8;
        pa[0] = *(const float4v*)s0; pa[1] = *(const float4v*)(s0 + 4);
        pa[2] = *(const float4v*)s1; pa[3] = *(const float4v*)(s1 + 4);
    };
    auto cvtWrite = [&](const float4v* pa, u16* dst) {
        u16x8 r0, r1;
        r0[0]=f2b(pa[0][0]); r0[1]=f2b(pa[0][1]); r0[2]=f2b(pa[0][2]); r0[3]=f2b(pa[0][3]);
        r0[4]=f2b(pa[1][0]); r0[5]=f2b(pa[1][1]); r0[6]=f2b(pa[1][2]); r0[7]=f2b(pa[1][3]);
        r1[0]=f2b(pa[2][0]); r1[1]=f2b(pa[2][1]); r1[2]=f2b(pa[2][2]); r1[3]=f2b(pa[2][3]);
        r1[4]=f2b(pa[3][0]); r1[5]=f2b(pa[3][1]); r1[6]=f2b(pa[3][2]); r1[7]=f2b(pa[3][3]);
        *(u16x8*)(dst + tid * 8) = r0;
        *(u16x8*)(dst + (tid + 512) * 8) = r1;
    };

    const int fsl  = lk ^ (lr & 3) ^ ((lr >> 2) & 3);
    const int aoff = (wm + lr) * 32 + fsl * 8;
    const int boff = (wn + lr) * 32 + fsl * 8;

    const int KT = K >> 5;   // K-tiles of 32

    if constexpr (AF32) {
        float4v p0[4];
        prefA32(0, p0);
        stageB(0, Bs0);
        prefA32(32, paB);
        stageB(32, Bs0 + 8192);
        cvtWrite(p0, As0);
        asm volatile("s_waitcnt lgkmcnt(0)" ::: "memory");
        asm volatile("s_waitcnt vmcnt(8)" ::: "memory");
    } else {
        stageA16(0, As0);          stageB(0, Bs0);
        stageA16(32, As0 + 8192);  stageB(32, Bs0 + 8192);
        asm volatile("s_waitcnt vmcnt(8)" ::: "memory");
    }
    __builtin_amdgcn_s_barrier();

    int sc = 0;
    for (int kt = 0; kt < KT; kt += 2) {
        const int sc1 = (sc == 2) ? 0 : sc + 1;
        const int sc2 = (sc1 == 2) ? 0 : sc1 + 1;
        u16* Ae = As0 + sc  * 8192;  u16* Be = Bs0 + sc  * 8192;
        u16* Ao = As0 + sc1 * 8192;  u16* Bo = Bs0 + sc1 * 8192;
        u16* A2 = As0 + sc2 * 8192;  u16* B2 = Bs0 + sc2 * 8192;
        const int k2 = (kt + 2 < KT) ? (kt + 2) << 5 : 0;
        const int k3 = (kt + 3 < KT) ? (kt + 3) << 5 : 0;
        TILE_BODY(Ae, Be, k2, A2, B2, Ao, paA, paB)
        TILE_BODY(Ao, Bo, k3, Ae, Be, A2, paB, paA)
        sc = sc2;
    }

    __syncthreads();

    const int r0 = lk * 4;
    float bvv[4];
#pragma unroll
    for (int ni = 0; ni < 4; ++ni) bvv[ni] = bias[nt + wn + ni * 16 + lr];
    const int half = w >> 2;
#pragma unroll
    for (int pass = 0; pass < 2; ++pass) {
        if (half == pass) {
#pragma unroll
            for (int mi = 0; mi < 8; ++mi)
#pragma unroll
                for (int ni = 0; ni < 4; ++ni) {
                    const int lc = wn + ni * 16 + lr;
#pragma unroll
                    for (int r = 0; r < 4; ++r) {
                        float v = acc[mi][ni][r] + bvv[ni];
                        if (ACT) v = v > 0.f ? v : 0.01f * v;
                        smem[(mi * 16 + r0 + r) * 264 + lc] = f2b(v);
                    }
                }
        }
        __syncthreads();
#pragma unroll
        for (int it = 0; it < 8; ++it) {
            const int id  = it * 512 + tid;
            const int row = id >> 5, colc = id & 31;
            u16x8 vv = *(const u16x8*)(smem + (size_t)row * 264 + colc * 8);
            *(u16x8*)(p.out[z] + (size_t)(mt + pass * 128 + row) * N + nt + colc * 8) = vv;
        }
        __syncthreads();
    }
}

// ---------------------------------------------------------------------------
// FINE-PHASE 256x128-tile bf16 GEMM (r5 skeleton, measured ~49us @K=1024).
// Used for GEMM2/GEMM3 (bf16 A). 512 thr = 8 waves (4Mx2N), acc[4][4],
// BK=64, LDS ring-3 (144 KB). Per tile: 2 phases of
//   { 8 ds_read_b128 | gld16 stage(T+2) | [ph1: vmcnt(6)] | s_barrier |
//     lgkmcnt(0) | setprio(1) 16 MFMA setprio(0) | s_barrier }.
// Generalized flat-grid XCD-chunked bijective swizzle (nblk % 8 == 0).
// ---------------------------------------------------------------------------
#define FPHASE(ASL, BSL, KH, STAGE, DO_VM)                                    \
    {                                                                         \
        short8 af[4], bq[4];                                                  \
        _Pragma("unroll") for (int mi = 0; mi < 4; ++mi)                      \
            af[mi] = *(const short8*)((ASL) +                                 \
                (size_t)(wm * 64 + mi * 16 + lr) * 64 +                       \
                (((KH) * 4 + lk) ^ (lr & 7)) * 8);                            \
        _Pragma("unroll") for (int ni = 0; ni < 4; ++ni)                      \
            bq[ni] = *(const short8*)((BSL) +                                 \
                (size_t)(wn * 64 + ni * 16 + lr) * 64 +                       \
                (((KH) * 4 + lk) ^ (lr & 7)) * 8);                            \
        STAGE;                                                                \
        if (DO_VM) asm volatile("s_waitcnt vmcnt(6)" ::: "memory");           \
        __builtin_amdgcn_s_barrier();                                         \
        asm volatile("s_waitcnt lgkmcnt(0)" ::: "memory");                    \
        __builtin_amdgcn_s_setprio(1);                                        \
        _Pragma("unroll") for (int mi = 0; mi < 4; ++mi)                      \
            _Pragma("unroll") for (int ni = 0; ni < 4; ++ni)                  \
                acc[mi][ni] = __builtin_amdgcn_mfma_f32_16x16x32_bf16(        \
                    af[mi], bq[ni], acc[mi][ni], 0, 0, 0);                    \
        __builtin_amdgcn_s_setprio(0);                                        \
        __builtin_amdgcn_s_barrier();                                         \
    }

template <int ACT>
__global__ __launch_bounds__(512, 2) void gemmt_k(GemmP p, int M, int N, int K) {
    __shared__ __align__(16) u16 smem[73728];   // 144 KB

    const int z = blockIdx.z;
    const u16*   __restrict__ Ag   = (const u16*)p.A[z];
    const u16*   __restrict__ Bg   = p.B[z];
    const float* __restrict__ bias = p.bias[z];

    // XCD-chunked bijective swizzle over flat grid (nblk % 8 == 0).
    const int nblk = gridDim.x;
    const int cpx  = nblk >> 3;
    const int flat = blockIdx.x;
    const int swz  = (flat & 7) * cpx + (flat >> 3);
    const int nbn  = N >> 7;
    const int mt   = (swz / nbn) * 256;
    const int nt   = (swz % nbn) * 128;

    const int tid = threadIdx.x;
    const int l   = tid & 63;
    const int w   = tid >> 6;
    const int wm  = w >> 1;           // 0..3  (64-row group)
    const int wn  = w & 1;            // 0..1  (64-col group)
    const int lr  = l & 15;
    const int lk  = l >> 4;
    (void)M;

    float4v acc[4][4] = {};

    const int srow   = tid >> 3;
    const int gchunk = (tid & 7) ^ (srow & 7);

    u16* const As0 = smem;            // A ring: 0, 16384, 32768 (u16)
    u16* const Bs0 = smem + 49152;    // B ring: +0, +8192, +16384

    auto stageA = [&](int k0, u16* dst) {
#pragma unroll
        for (int i = 0; i < 4; ++i)
            gld16(Ag + (size_t)(mt + srow + 64 * i) * K + k0 + gchunk * 8,
                  dst + (size_t)(tid + 512 * i) * 8);
    };
    auto stageB = [&](int k0, u16* dst) {
#pragma unroll
        for (int i = 0; i < 2; ++i)
            gld16(Bg + (size_t)(nt + srow + 64 * i) * K + k0 + gchunk * 8,
                  dst + (size_t)(tid + 512 * i) * 8);
    };

    const int NT = K >> 6;   // K-tiles of 64 (8 for G2, 4 for G3)

    stageA(0, As0);          stageB(0, Bs0);
    stageA(64, As0 + 16384); stageB(64, Bs0 + 8192);
    asm volatile("s_waitcnt vmcnt(6)" ::: "memory");   // tile 0 landed
    __builtin_amdgcn_s_barrier();

    int sc = 0;
    for (int T = 0; T < NT; ++T) {
        const int sc2 = (sc >= 1) ? sc - 1 : 2;        // (T+2)%3
        u16* Ac = As0 + sc  * 16384;  u16* Bc = Bs0 + sc  * 8192;
        u16* A2 = As0 + sc2 * 16384;  u16* B2 = Bs0 + sc2 * 8192;
        const int k2 = (T + 2 < NT) ? (T + 2) << 6 : 0;   // clamp keeps vmcnt
        FPHASE(Ac, Bc, 0, stageA(k2, A2), 0)
        FPHASE(Ac, Bc, 1, stageB(k2, B2), 1)
        sc = (sc == 2) ? 0 : sc + 1;
    }

    __syncthreads();   // full drain: tail gld16 DMA must land before LDS reuse

    const int er0 = lk * 4;
    float bvv[4];
#pragma unroll
    for (int ni = 0; ni < 4; ++ni) bvv[ni] = bias[nt + wn * 64 + ni * 16 + lr];
#pragma unroll
    for (int mi = 0; mi < 4; ++mi)
#pragma unroll
        for (int ni = 0; ni < 4; ++ni) {
            const int lc = wn * 64 + ni * 16 + lr;
#pragma unroll
            for (int r = 0; r < 4; ++r) {
                float v = acc[mi][ni][r] + bvv[ni];
                if (ACT) v = v > 0.f ? v : 0.01f * v;
                smem[(size_t)(wm * 64 + mi * 16 + er0 + r) * 136 + lc] = f2b(v);
            }
        }
    __syncthreads();
#pragma unroll
    for (int it = 0; it < 8; ++it) {
        const int id  = it * 512 + tid;
        const int row = id >> 4, colc = id & 15;
        u16x8 vv = *(const u16x8*)(smem + (size_t)row * 136 + colc * 8);
        *(u16x8*)(p.out[z] + (size_t)(mt + row) * N + nt + colc * 8) = vv;
    }
}

// ---------------------------------------------------------------------------
// LDS-tiled weight transpose+convert: fp32 [K,N] -> bf16 [N,K], 64x64 tiles
// ---------------------------------------------------------------------------
struct TP { const float* src[6]; u16* dst[6]; int K[6]; int N[6]; };

__global__ __launch_bounds__(256) void transpose_k(TP t) {
    __shared__ float tile[64][65];
    const int m = blockIdx.y;
    const int K = t.K[m], N = t.N[m];
    const int tn = N >> 6;
    const int ntiles = (K >> 6) * tn;
    const int bid = blockIdx.x;
    if (bid >= ntiles) return;
    const int k0 = (bid / tn) * 64, n0 = (bid % tn) * 64;
    const int tid = threadIdx.x;
#pragma unroll
    for (int pass = 0; pass < 4; ++pass) {
        int kk = pass * 16 + (tid >> 4);
        int nn = (tid & 15) * 4;
        float4v v = *(const float4v*)(t.src[m] + (size_t)(k0 + kk) * N + n0 + nn);
        tile[kk][nn + 0] = v[0]; tile[kk][nn + 1] = v[1];
        tile[kk][nn + 2] = v[2]; tile[kk][nn + 3] = v[3];
    }
    __syncthreads();
    const int n = tid >> 2, kc = (tid & 3) * 16;
    u16x8 a, b;
#pragma unroll
    for (int j = 0; j < 8; ++j) {
        a[j] = f2b(tile[kc + j][n]);
        b[j] = f2b(tile[kc + 8 + j][n]);
    }
    u16* d = t.dst[m] + (size_t)(n0 + n) * K + k0 + kc;
    *(u16x8*)d = a;
    *(u16x8*)(d + 8) = b;
}

// EW[t][c] = sum_e emb[t][e] * W_edge[e][c]  (64x256 fp32, 4 partials for ILP)
__global__ void ew_k(const float* emb, const float* W_edge, float* EW) {
    const int t = blockIdx.x, c = threadIdx.x;
    float p0 = 0.f, p1 = 0.f, p2 = 0.f, p3 = 0.f;
    for (int e = 0; e < 64; e += 4) {
        p0 += emb[t * 64 + e + 0] * W_edge[(e + 0) * 256 + c];
        p1 += emb[t * 64 + e + 1] * W_edge[(e + 1) * 256 + c];
        p2 += emb[t * 64 + e + 2] * W_edge[(e + 2) * 256 + c];
        p3 += emb[t * 64 + e + 3] * W_edge[(e + 3) * 256 + c];
    }
    EW[t * 256 + c] = (p0 + p1) + (p2 + p3);
}

// bcat = [b_msg | b_self]  (512 fp32)
__global__ void bias_cat_k(const float* bmsg, const float* bself, float* bcat) {
    const int tid = threadIdx.x;
    bcat[tid]       = bmsg[tid];
    bcat[256 + tid] = bself[tid];
}

// ---------------------------------------------------------------------------
// Epilogue: out_i = xself[i] + valid_i*(xmsg[head_i] + EW[type_i]);
//           L2-normalize; accumulate per-batch sum (later /2048).
// alpha == valid exactly (dst=arange -> singleton segments -> softmax = 1).
// ---------------------------------------------------------------------------
struct EpiP {
    const u16* xcat[2];
    const int* den[2]; const int* spa[2]; const int* arc[2];
    const int* wty[2]; const int* wma[2];
    const float* EW; float* racc;
};

__global__ __launch_bounds__(256) void epi_k(EpiP p) {
    __shared__ float part[4][256];
    const int bx    = blockIdx.x;
    const int side  = bx >> 9;           // 512 blocks per side
    const int local = bx & 511;
    const int base  = local * 32;        // 32 nodes/block (same batch: 32|2048)
    const int b     = base >> 11;
    const int tid   = threadIdx.x;
    const int w = tid >> 6, l = tid & 63;

    const u16* __restrict__ xcat = p.xcat[side];

    float4v acc = {};
    for (int j = 0; j < 8; ++j) {
        const int i     = base + w * 8 + j;
        const int valid = p.den[side][i] * p.spa[side][i];
        const int srcn  = p.arc[side][i] + (i >> 11) * SEQ;
        const int t     = p.wty[side][i] * p.wma[side][i];
        short4v xs = *(const short4v*)(xcat + (size_t)i * 512 + 256 + l * 4);
        short4v xm = *(const short4v*)(xcat + (size_t)srcn * 512 + l * 4);
        float4v ew = *(const float4v*)(p.EW + (size_t)t * 256 + l * 4);
        const float vm = valid ? 1.f : 0.f;
        float4v v;
        v[0] = b2f((u16)xs[0]) + vm * (b2f((u16)xm[0]) + ew[0]);
        v[1] = b2f((u16)xs[1]) + vm * (b2f((u16)xm[1]) + ew[1]);
        v[2] = b2f((u16)xs[2]) + vm * (b2f((u16)xm[2]) + ew[2]);
        v[3] = b2f((u16)xs[3]) + vm * (b2f((u16)xm[3]) + ew[3]);
        float ss = v[0]*v[0] + v[1]*v[1] + v[2]*v[2] + v[3]*v[3];
        for (int m = 32; m >= 1; m >>= 1) ss += __shfl_xor(ss, m, 64);
        const float rn = 1.f / fmaxf(sqrtf(ss), 1e-12f);
        acc[0] += v[0] * rn; acc[1] += v[1] * rn;
        acc[2] += v[2] * rn; acc[3] += v[3] * rn;
    }
    part[w][l * 4 + 0] = acc[0];
    part[w][l * 4 + 1] = acc[1];
    part[w][l * 4 + 2] = acc[2];
    part[w][l * 4 + 3] = acc[3];
    __syncthreads();
    const float s = part[0][tid] + part[1][tid] + part[2][tid] + part[3][tid];
    atomicAdd(p.racc + ((size_t)side * 8 + b) * 256 + tid, s);
}

// out[side,b,c] = (racc[side,b,:]/2048) @ Wf[:,c] + bf[c]   (fp32 out)
__global__ void fin_k(const float* racc, const float* Wf, const float* bfv,
                      float* out) {
    __shared__ float r[256];
    const int bid = blockIdx.x;   // side*8 + b, 0..15
    const int tid = threadIdx.x;
    r[tid] = racc[bid * 256 + tid] * (1.f / 2048.f);
    __syncthreads();
    float s = bfv[tid];
    for (int k = 0; k < 256; ++k)
        s += r[k] * Wf[k * 256 + tid];
    out[bid * 256 + tid] = s;
}

// ---------------------------------------------------------------------------
extern "C" void kernel_launch(void* const* d_in, const int* in_sizes, int n_in,
                              void* d_out, int out_size, void* d_ws, size_t ws_size,
                              hipStream_t stream) {
    // setup_inputs() dict order; float tensors fp32, index tensors int32
    const float* h[2]   = {(const float*)d_in[0],  (const float*)d_in[1]};
    const int* den[2]   = {(const int*)d_in[4],  (const int*)d_in[11]};
    const int* spa[2]   = {(const int*)d_in[5],  (const int*)d_in[12]};
    const int* arc[2]   = {(const int*)d_in[7],  (const int*)d_in[14]};
    const int* wty[2]   = {(const int*)d_in[9],  (const int*)d_in[16]};
    const int* wma[2]   = {(const int*)d_in[10], (const int*)d_in[17]};
    const float* W1[2]  = {(const float*)d_in[18], (const float*)d_in[22]};
    const float* b1[2]  = {(const float*)d_in[19], (const float*)d_in[23]};
    const float* W2[2]  = {(const float*)d_in[20], (const float*)d_in[24]};
    const float* b2[2]  = {(const float*)d_in[21], (const float*)d_in[25]};
    const float* emb    = (const float*)d_in[26];
    const float* Wmsg   = (const float*)d_in[27];
    const float* bmsg   = (const float*)d_in[28];
    const float* Wedge  = (const float*)d_in[29];
    const float* Wself  = (const float*)d_in[31];
    const float* bself  = (const float*)d_in[32];
    const float* Wf     = (const float*)d_in[33];
    const float* bf_    = (const float*)d_in[34];

    char* ws = (char*)d_ws;
    size_t off = 0;
    auto alloc = [&](size_t bytes) -> void* {
        void* pp = ws + off; off += (bytes + 255) & ~(size_t)255; return pp;
    };
    u16*   x1    = (u16*)  alloc(2ull * NNODE * 512 * 2);   // 32 MB, MLP hidden
    u16*   xx    = (u16*)  alloc(2ull * NNODE * 256 * 2);   // 16 MB, x
    u16*   xcat  = (u16*)  alloc(2ull * NNODE * 512 * 2);   // 32 MB, [msg|self]
    u16*   W1T   = (u16*)  alloc(2ull * 512 * 1024 * 2);
    u16*   W2T   = (u16*)  alloc(2ull * 256 * 512 * 2);
    u16*   WcatT = (u16*)  alloc(512 * 256 * 2);            // [WmsgT ; WselfT]
    float* EW    = (float*)alloc(64 * 256 * 4);
    float* bcat  = (float*)alloc(512 * 4);
    float* racc  = (float*)alloc(2 * 8 * 256 * 4);

    // prep: weights transpose+convert to [N,K] bf16 (LDS-tiled, coalesced)
    TP tp;
    tp.src[0] = W1[0]; tp.dst[0] = W1T;              tp.K[0] = 1024; tp.N[0] = 512;
    tp.src[1] = W1[1]; tp.dst[1] = W1T + 512 * 1024; tp.K[1] = 1024; tp.N[1] = 512;
    tp.src[2] = W2[0]; tp.dst[2] = W2T;              tp.K[2] = 512;  tp.N[2] = 256;
    tp.src[3] = W2[1]; tp.dst[3] = W2T + 256 * 512;  tp.K[3] = 512;  tp.N[3] = 256;
    tp.src[4] = Wmsg;  tp.dst[4] = WcatT;            tp.K[4] = 256;  tp.N[4] = 256;
    tp.src[5] = Wself; tp.dst[5] = WcatT + 256*256;  tp.K[5] = 256;  tp.N[5] = 256;
    hipLaunchKernelGGL(transpose_k, dim3(128, 6), dim3(256), 0, stream, tp);
    hipLaunchKernelGGL(ew_k, dim3(64), dim3(256), 0, stream, emb, Wedge, EW);
    hipLaunchKernelGGL(bias_cat_k, dim3(1), dim3(256), 0, stream, bmsg, bself, bcat);
    hipMemsetAsync(racc, 0, 2 * 8 * 256 * 4, stream);

    // GEMM1 (coarse, fused fp32->bf16 A): [16384,1024]@[1024,512]+b1, leaky
    GemmP g1 = {};
    g1.A[0] = h[0];  g1.A[1] = h[1];
    g1.B[0] = W1T;   g1.B[1] = W1T + 512 * 1024;
    g1.bias[0] = b1[0]; g1.bias[1] = b1[1];
    g1.out[0] = x1;  g1.out[1] = x1 + (size_t)NNODE * 512;
    hipLaunchKernelGGL((gemm8_k<1, 1>), dim3(64, 2, 2), dim3(512), 0, stream,
                       g1, NNODE, 512, 1024);

    // GEMM2 (fine-phase): [16384,512]@[512,256] + b2 -> xx (bf16)
    GemmP g2 = {};
    g2.A[0] = x1;  g2.A[1] = x1 + (size_t)NNODE * 512;
    g2.B[0] = W2T; g2.B[1] = W2T + 256 * 512;
    g2.bias[0] = b2[0]; g2.bias[1] = b2[1];
    g2.out[0] = xx; g2.out[1] = xx + (size_t)NNODE * 256;
    hipLaunchKernelGGL((gemmt_k<0>), dim3(128, 1, 2), dim3(512), 0, stream,
                       g2, NNODE, 256, 512);

    // GEMM3 (fine-phase, merged msg|self): [16384,256]@[256,512]+bcat -> xcat
    GemmP g3 = {};
    g3.A[0] = xx;    g3.A[1] = xx + (size_t)NNODE * 256;
    g3.B[0] = WcatT; g3.B[1] = WcatT;
    g3.bias[0] = bcat; g3.bias[1] = bcat;
    g3.out[0] = xcat;  g3.out[1] = xcat + (size_t)NNODE * 512;
    hipLaunchKernelGGL((gemmt_k<0>), dim3(256, 1, 2), dim3(512), 0, stream,
                       g3, NNODE, 512, 256);

    // gather + mask + L2-normalize + per-batch mean accumulation
    EpiP ep;
    ep.xcat[0] = xcat; ep.xcat[1] = xcat + (size_t)NNODE * 512;
    for (int s = 0; s < 2; ++s) {
        ep.den[s] = den[s]; ep.spa[s] = spa[s]; ep.arc[s] = arc[s];
        ep.wty[s] = wty[s]; ep.wma[s] = wma[s];
    }
    ep.EW = EW; ep.racc = racc;
    hipLaunchKernelGGL(epi_k, dim3(1024), dim3(256), 0, stream, ep);

    // final projection -> d_out (fp32, src then tgt, 2*8*256)
    hipLaunchKernelGGL(fin_k, dim3(16), dim3(256), 0, stream,
                       racc, Wf, bf_, (float*)d_out);
}